// Round 13
// baseline (377.054 us; speedup 1.0000x reference)
//
#include <hip/hip_runtime.h>
#include <hip/hip_bf16.h>

// Problem constants (fixed by reference)
static constexpr int NN = 20000;   // nodes
static constexpr int EE = 320000;  // edges (without self loops)
static constexpr int ET = EE + NN; // edges incl self loops = 340000
static constexpr int DD = 512;     // hidden dim
static constexpr int FIN = 128;    // input features

// src-chunked CSR: cluster each dst row's edges by src chunk (2048 rows = 2 MB of h)
// so concurrently-resident gather waves share an L2-sized src window.
static constexpr int CSH = 11;                  // chunk shift (2048 src rows)
static constexpr int NCH = (NN + (1 << CSH) - 1) >> CSH; // 10 chunks

typedef __attribute__((ext_vector_type(8))) short short8; // 8 bf16 (4 VGPRs)
typedef __attribute__((ext_vector_type(4))) float f32x4;  // MFMA C/D frag

// float -> bf16 (round to nearest even), raw ushort bits
__device__ __forceinline__ unsigned short f2bf(float f) {
    unsigned u = __float_as_uint(f);
    u += 0x7fffu + ((u >> 16) & 1u);
    return (unsigned short)(u >> 16);
}
__device__ __forceinline__ float bf2f(unsigned short b) {
    return __uint_as_float(((unsigned)b) << 16);
}

// async global->LDS DMA, 16 B per lane. LDS dest = wave-uniform base + lane*16.
__device__ __forceinline__ void async_copy16(short* lds, const unsigned short* g) {
    __builtin_amdgcn_global_load_lds(
        (const __attribute__((address_space(1))) unsigned int*)g,
        (__attribute__((address_space(3))) unsigned int*)lds,
        16, 0, 0);
}

// ---------- init: deg + per-(dst,chunk) counters + edge-index dtype detection ----------
// deg[i]=1 and cnt2[i][chunk(i)]=1 pre-count the self-loop; cur2 zeroed.
__global__ void init_k(int* __restrict__ deg, int* __restrict__ cnt2,
                       int* __restrict__ cur2, const unsigned* __restrict__ ei,
                       int* __restrict__ flag) {
    int i = blockIdx.x * blockDim.x + threadIdx.x;
    if (i < NN) {
        deg[i] = 1;
        int kself = i >> CSH;
#pragma unroll
        for (int k = 0; k < NCH; ++k) {
            cnt2[i * NCH + k] = (k == kself) ? 1 : 0;
            cur2[i * NCH + k] = 0;
        }
    }
    if (i == 0) {
        int is64 = 1;
        for (int j = 0; j < 64; ++j)
            if (ei[2 * j + 1] != 0u) { is64 = 0; break; }
        *flag = is64;
    }
}

// count in-degree + per-(dst, src-chunk) histogram of real edges
__global__ void count_deg(const void* __restrict__ ei, const int* __restrict__ flag,
                          int* __restrict__ deg, int* __restrict__ cnt2) {
    int i = blockIdx.x * blockDim.x + threadIdx.x;
    if (i >= EE) return;
    int s, d;
    if (*flag) {
        const long long* p = (const long long*)ei;
        s = (int)p[i]; d = (int)p[EE + i];
    } else {
        const int* p = (const int*)ei;
        s = p[i]; d = p[EE + i];
    }
    atomicAdd(&deg[d], 1);
    atomicAdd(&cnt2[d * NCH + (s >> CSH)], 1);
}

__global__ void scan_k(const int* __restrict__ deg, int* __restrict__ row_ptr) {
    __shared__ int part[1024];
    int t = threadIdx.x;
    const int CH = (NN + 1023) / 1024; // 20
    int start = t * CH;
    int end = min(start + CH, NN);
    int s = 0;
    for (int i = start; i < end; ++i) s += deg[i];
    part[t] = s;
    __syncthreads();
    for (int off = 1; off < 1024; off <<= 1) {
        int v = 0;
        if (t >= off) v = part[t - off];
        __syncthreads();
        part[t] += v;
        __syncthreads();
    }
    int base = (t == 0) ? 0 : part[t - 1];
    for (int i = start; i < end; ++i) { row_ptr[i] = base; base += deg[i]; }
    if (t == 1023) row_ptr[NN] = part[1023];
}

// per-row chunk bases: base2[d][k] = row_ptr[d] + prefix of cnt2[d][:k]
__global__ void base_k(const int* __restrict__ row_ptr, const int* __restrict__ cnt2,
                       int* __restrict__ base2) {
    int d = blockIdx.x * blockDim.x + threadIdx.x;
    if (d >= NN) return;
    int run = row_ptr[d];
#pragma unroll
    for (int k = 0; k < NCH; ++k) {
        base2[d * NCH + k] = run;
        run += cnt2[d * NCH + k];
    }
}

// chunked-stable CSR fill: each dst row's src list is grouped by src chunk
__global__ void fill_csr(const void* __restrict__ ei, const int* __restrict__ flag,
                         const int* __restrict__ base2, int* __restrict__ cur2,
                         int* __restrict__ csr_src) {
    int e = blockIdx.x * blockDim.x + threadIdx.x;
    if (e >= ET) return;
    int s, d;
    if (e < EE) {
        if (*flag) {
            const long long* p = (const long long*)ei;
            s = (int)p[e]; d = (int)p[EE + e];
        } else {
            const int* p = (const int*)ei;
            s = p[e]; d = p[EE + e];
        }
    } else {
        s = d = e - EE;
    }
    int idx2 = d * NCH + (s >> CSH);
    int pos = atomicAdd(&cur2[idx2], 1);
    csr_src[base2[idx2] + pos] = s;
}

// ---------- merged prep: LDS-tiled weight transpose (blocks 0..207) + x->bf16 + zero-init ----------
static constexpr int TBLK = 208;                // transpose tile blocks (16 + 3*64)
static constexpr int SZ_X = NN * FIN;           // 2,560,000
static constexpr int SZ_Z = 2 * 1024 + 2 * NN;  // bnstatA/B + al_s2 + al_d2
__global__ __launch_bounds__(256) void prep_all_k(
    const float* __restrict__ x, const float* __restrict__ W1,
    const float* __restrict__ fc1, const float* __restrict__ W2,
    const float* __restrict__ fc2,
    unsigned short* __restrict__ xb, unsigned short* __restrict__ W1t,
    unsigned short* __restrict__ fc1t, unsigned short* __restrict__ W2t,
    unsigned short* __restrict__ fc2t,
    float* __restrict__ bnstatA, float* __restrict__ bnstatB,
    float* __restrict__ al_s2, float* __restrict__ al_d2) {
    int b = blockIdx.x;
    if (b < TBLK) { // 64x64 transpose tiles, coalesced reads AND writes
        __shared__ unsigned short tile[64][65];
        const float* src; unsigned short* dst; int rows, cols;
        if (b < 16)       { src = W1;  dst = W1t;  rows = FIN; cols = DD; }
        else if (b < 80)  { b -= 16;  src = fc1; dst = fc1t; rows = DD; cols = DD; }
        else if (b < 144) { b -= 80;  src = W2;  dst = W2t;  rows = DD; cols = DD; }
        else              { b -= 144; src = fc2; dst = fc2t; rows = DD; cols = DD; }
        int tc = cols / 64;
        int r0 = (b / tc) * 64, c0 = (b % tc) * 64;
        int t = threadIdx.x, lr = t >> 6, lc = t & 63;
#pragma unroll
        for (int p = 0; p < 16; ++p) {
            int r = lr + p * 4;
            tile[r][lc] = f2bf(src[(size_t)(r0 + r) * cols + c0 + lc]);
        }
        __syncthreads();
#pragma unroll
        for (int p = 0; p < 16; ++p) {
            int r = lr + p * 4; // output row = source col
            dst[(size_t)(c0 + r) * rows + r0 + lc] = tile[lc][r];
        }
        return;
    }
    int i = (b - TBLK) * 256 + threadIdx.x;
    if (i < SZ_X) { xb[i] = f2bf(x[i]); return; }
    i -= SZ_X;
    if (i < 1024) { bnstatA[i] = 0.f; return; }
    i -= 1024;
    if (i < 1024) { bnstatB[i] = 0.f; return; }
    i -= 1024;
    if (i < NN) { al_s2[i] = 0.f; return; }
    i -= NN;
    if (i < NN) { al_d2[i] = 0.f; return; }
}

// ---------- bf16 MFMA GEMM: Cb[M,Nc] = bf16( A[M,K] @ Bt[Nc,K]^T (+bias)(+relu) ) ----------
// 128x128 tile, BK=64 (two 32-elem half-tiles), 256 threads = 4 waves (2x2),
// each wave 4x4 tiles of 16x16x32. Staging via async global_load_lds (16 B/lane).
// XCD-aware swizzle: 640 blocks (160 padded m-tiles x 4 n-tiles);
// bm = 8*(id/32) + id%8, bn = (id/8)&3.
// STATS: fused per-column BN sum/sumsq of post-relu fp32 C into bnstat.
// ALS: fused attention logits al_s/al_d = C . avs/avd (per row, per head).
template <int RELU, int HASBIAS, int STATS, int ALS, int H>
__global__ __launch_bounds__(256) void gemm_bf16(const unsigned short* __restrict__ A,
                                                 const unsigned short* __restrict__ Bt,
                                                 const float* __restrict__ bias,
                                                 unsigned short* __restrict__ Cb,
                                                 float* __restrict__ bnstat,
                                                 const float* __restrict__ avs,
                                                 const float* __restrict__ avd,
                                                 float* __restrict__ al_s,
                                                 float* __restrict__ al_d,
                                                 int M, int Nc, int K) {
    int id = blockIdx.x;
    int bm = ((id >> 5) << 3) + (id & 7); // 0..159
    int bn = (id >> 3) & 3;               // 0..3
    int m0 = bm * 128, n0 = bn * 128;
    if (m0 >= M) return; // padded m-tiles: whole block exits (no barrier executed)

    __shared__ short As0[128 * 32], As1[128 * 32]; // k-halves, 8 KB each
    __shared__ short Bs0[128 * 32], Bs1[128 * 32];
    int t = threadIdx.x;
    int lane = t & 63, w = t >> 6;
    int wm = w & 1, wn = w >> 1;           // wave quadrant (2x2 of 64x64)
    int quad = lane >> 4, mr = lane & 15;  // MFMA fragment indices
    int lrow = lane >> 2;                  // staging: row within 16-row group
    int lcol = (lane & 3) * 8;             // staging: elem offset within 32-elem half-row

    const unsigned short* Ag0 = A + (size_t)(m0 + w * 32 + lrow) * K + lcol;
    const unsigned short* Ag1 = A + (size_t)(m0 + w * 32 + 16 + lrow) * K + lcol;
    const unsigned short* Bg0 = Bt + (size_t)(n0 + w * 32 + lrow) * K + lcol;
    const unsigned short* Bg1 = Bt + (size_t)(n0 + w * 32 + 16 + lrow) * K + lcol;
    short* Al[2][2] = {{&As0[(w * 32) * 32], &As0[(w * 32 + 16) * 32]},
                       {&As1[(w * 32) * 32], &As1[(w * 32 + 16) * 32]}};
    short* Bl[2][2] = {{&Bs0[(w * 32) * 32], &Bs0[(w * 32 + 16) * 32]},
                       {&Bs1[(w * 32) * 32], &Bs1[(w * 32 + 16) * 32]}};

    f32x4 zero = {0.f, 0.f, 0.f, 0.f};
    f32x4 acc[4][4];
#pragma unroll
    for (int i = 0; i < 4; ++i)
#pragma unroll
        for (int j = 0; j < 4; ++j) acc[i][j] = zero;

    for (int k0 = 0; k0 < K; k0 += 64) {
        async_copy16(Al[0][0], Ag0 + k0);
        async_copy16(Al[1][0], Ag0 + k0 + 32);
        async_copy16(Al[0][1], Ag1 + k0);
        async_copy16(Al[1][1], Ag1 + k0 + 32);
        async_copy16(Bl[0][0], Bg0 + k0);
        async_copy16(Bl[1][0], Bg0 + k0 + 32);
        async_copy16(Bl[0][1], Bg1 + k0);
        async_copy16(Bl[1][1], Bg1 + k0 + 32);
        __syncthreads(); // drains vmcnt(0): DMA data landed in LDS
#pragma unroll
        for (int kp = 0; kp < 2; ++kp) {
            const short* Sa = kp ? As1 : As0;
            const short* Sb = kp ? Bs1 : Bs0;
            short8 af[4], bfr[4];
#pragma unroll
            for (int i = 0; i < 4; ++i) {
                af[i]  = *(const short8*)(&Sa[(wm * 64 + i * 16 + mr) * 32 + quad * 8]);
                bfr[i] = *(const short8*)(&Sb[(wn * 64 + i * 16 + mr) * 32 + quad * 8]);
            }
#pragma unroll
            for (int i = 0; i < 4; ++i)
#pragma unroll
                for (int j = 0; j < 4; ++j)
                    acc[i][j] = __builtin_amdgcn_mfma_f32_16x16x32_bf16(af[i], bfr[j], acc[i][j], 0, 0, 0);
        }
        __syncthreads(); // all waves done reading before next DMA overwrites
    }

    // epilogue: C/D layout col = lane&15, row = (lane>>4)*4 + reg  [m89/m91]
    float as_j[4], ad_j[4];
    if (ALS) {
#pragma unroll
        for (int j = 0; j < 4; ++j) {
            int n = n0 + wn * 64 + j * 16 + mr;
            as_j[j] = avs[n]; // a[H][C] flat == global col index for both H=8 and H=1
            ad_j[j] = avd[n];
        }
    }
    const int head = (H == 8) ? ((n0 + wn * 64) >> 6) : 0;
    float sj[4] = {0.f, 0.f, 0.f, 0.f}, qj[4] = {0.f, 0.f, 0.f, 0.f};
#pragma unroll
    for (int i = 0; i < 4; ++i) {
        int mb = m0 + wm * 64 + i * 16 + quad * 4;
#pragma unroll
        for (int r = 0; r < 4; ++r) {
            int m = mb + r;               // uniform across the 16 mr-lanes
            bool valid = (m < M);
            float ps = 0.f, pd = 0.f;
#pragma unroll
            for (int j = 0; j < 4; ++j) {
                int n = n0 + wn * 64 + j * 16 + mr;
                float v = acc[i][j][r];
                if (HASBIAS) v += bias[n];
                if (RELU) v = fmaxf(v, 0.f);
                unsigned short hb = f2bf(v);
                if (valid) Cb[(size_t)m * Nc + n] = hb;
                if (ALS) {
                    float vv = bf2f(hb); // match downstream bf16 read
                    ps += as_j[j] * vv;
                    pd += ad_j[j] * vv;
                }
                if (STATS && valid) { sj[j] += v; qj[j] += v * v; }
            }
            if (ALS) {
                ps += __shfl_xor(ps, 1); pd += __shfl_xor(pd, 1);
                ps += __shfl_xor(ps, 2); pd += __shfl_xor(pd, 2);
                ps += __shfl_xor(ps, 4); pd += __shfl_xor(pd, 4);
                ps += __shfl_xor(ps, 8); pd += __shfl_xor(pd, 8);
                if (mr == 0 && valid) {
                    if (H == 8) { al_s[m * 8 + head] = ps; al_d[m * 8 + head] = pd; }
                    else        { atomicAdd(&al_s[m], ps); atomicAdd(&al_d[m], pd); }
                }
            }
        }
    }
    if (STATS) {
#pragma unroll
        for (int j = 0; j < 4; ++j) {
            float s = sj[j], q = qj[j];
            s += __shfl_xor(s, 16); q += __shfl_xor(q, 16);
            s += __shfl_xor(s, 32); q += __shfl_xor(q, 32);
            if (lane < 16) { // quad==0 holds the 4-row-group total for this column
                int n = n0 + wn * 64 + j * 16 + mr;
                atomicAdd(&bnstat[n], s);
                atomicAdd(&bnstat[512 + n], q);
            }
        }
    }
}

// ---------- fused softmax + gather-aggregate: one WAVE per node ----------
// csr_src is chunk-sorted by src: resident waves share an L2-sized src window.
template <int H>
__global__ __launch_bounds__(256) void gat_gather_k(const unsigned short* __restrict__ hb,
                                                    const float* __restrict__ al_s,
                                                    const float* __restrict__ al_d,
                                                    const int* __restrict__ row_ptr,
                                                    const int* __restrict__ csr_src,
                                                    const float* __restrict__ bias,
                                                    unsigned short* __restrict__ outb) {
    int t = threadIdx.x;
    int w = t >> 6, lane = t & 63;
    int n = blockIdx.x * 4 + w; // NN % 4 == 0
    int beg = row_ptr[n], end = row_ptr[n + 1];
    const int hh = (H == 8) ? (lane >> 3) : 0;
    float ald = al_d[n * H + hh];
    float psum = 0.f;
    float acc[8] = {0.f, 0.f, 0.f, 0.f, 0.f, 0.f, 0.f, 0.f};

    for (int p0 = beg; p0 < end; p0 += 64) {
        int cnt = min(64, end - p0);
        int sv = (p0 + lane < end) ? csr_src[p0 + lane] : 0;
        int p = 0;
        for (; p + 8 <= cnt; p += 8) {
            int sn[8];
#pragma unroll
            for (int u = 0; u < 8; ++u) sn[u] = __shfl(sv, p + u);
            float l[8];
#pragma unroll
            for (int u = 0; u < 8; ++u) l[u] = al_s[sn[u] * H + hh] + ald;
            short8 hv[8];
#pragma unroll
            for (int u = 0; u < 8; ++u)
                hv[u] = *(const short8*)(hb + (size_t)sn[u] * DD + lane * 8);
            float a[8];
#pragma unroll
            for (int u = 0; u < 8; ++u) {
                float xx = l[u];
                a[u] = __expf((xx > 0.f) ? xx : 0.2f * xx);
                psum += a[u];
            }
#pragma unroll
            for (int u = 0; u < 8; ++u)
#pragma unroll
                for (int j = 0; j < 8; ++j) acc[j] += a[u] * bf2f((unsigned short)hv[u][j]);
        }
        for (; p < cnt; ++p) {
            int sn0 = __shfl(sv, p);
            float l0 = al_s[sn0 * H + hh] + ald;
            short8 h0 = *(const short8*)(hb + (size_t)sn0 * DD + lane * 8);
            float a0 = __expf((l0 > 0.f) ? l0 : 0.2f * l0);
            psum += a0;
#pragma unroll
            for (int j = 0; j < 8; ++j) acc[j] += a0 * bf2f((unsigned short)h0[j]);
        }
    }
    float inv = 1.0f / psum;
    unsigned short ov[8];
#pragma unroll
    for (int j = 0; j < 8; ++j) ov[j] = f2bf(acc[j] * inv + bias[lane * 8 + j]);
    *(int4*)(outb + (size_t)n * DD + lane * 8) = *(const int4*)ov;
}

// ---------- fold BN1 into W2: W2t[n][k] *= sc[k] (in place); bias2[n] = sum_k sh[k]*W2t[n][k] ----------
__global__ __launch_bounds__(256) void fold1_k(const float* __restrict__ stat,
                                               const float* __restrict__ g,
                                               const float* __restrict__ be,
                                               unsigned short* __restrict__ W2t,
                                               float* __restrict__ bias2) {
    int t = threadIdx.x;
    int n = blockIdx.x * 4 + (t >> 6); // 128 blocks -> n in [0,512)
    int lane = t & 63;
    float pb = 0.f;
#pragma unroll
    for (int j = 0; j < 8; ++j) {
        int k = lane * 8 + j;
        float mean = stat[k] * (1.0f / NN);
        float var = stat[512 + k] * (1.0f / NN) - mean * mean;
        float sc = g[k] * rsqrtf(var + 1e-5f);
        float sh = be[k] - mean * sc;
        float wv = bf2f(W2t[n * DD + k]);
        W2t[n * DD + k] = f2bf(sc * wv);
        pb += sh * wv;
    }
    for (int off = 32; off; off >>= 1) pb += __shfl_down(pb, off);
    if (lane == 0) bias2[n] = pb;
}

// ---------- final linear [D,2] + relu (wave per node), BN2 computed inline per lane ----------
__global__ void final_linear(const unsigned short* __restrict__ xb,
                             const float* __restrict__ stat, const float* __restrict__ g,
                             const float* __restrict__ be, const float* __restrict__ w,
                             const float* __restrict__ b, float* __restrict__ out) {
    int wave = (blockIdx.x * blockDim.x + threadIdx.x) >> 6;
    int lane = threadIdx.x & 63;
    if (wave >= NN) return;
    short8 hv = *(const short8*)(xb + (size_t)wave * DD + lane * 8);
    float p0 = 0.f, p1 = 0.f;
#pragma unroll
    for (int j = 0; j < 8; ++j) {
        int c = lane * 8 + j;
        float mean = stat[c] * (1.0f / NN);
        float var = stat[512 + c] * (1.0f / NN) - mean * mean;
        float sc = g[c] * rsqrtf(var + 1e-5f);
        float vn = (bf2f((unsigned short)hv[j]) - mean) * sc + be[c];
        p0 += vn * w[2 * c];
        p1 += vn * w[2 * c + 1];
    }
    for (int off = 32; off; off >>= 1) {
        p0 += __shfl_down(p0, off);
        p1 += __shfl_down(p1, off);
    }
    if (lane == 0) {
        out[wave * 2 + 0] = fmaxf(p0 + b[0], 0.f);
        out[wave * 2 + 1] = fmaxf(p1 + b[1], 0.f);
    }
}

extern "C" void kernel_launch(void* const* d_in, const int* in_sizes, int n_in,
                              void* d_out, int out_size, void* d_ws, size_t ws_size,
                              hipStream_t stream) {
    const float* x     = (const float*)d_in[0];
    const void*  ei    = d_in[1];
    const float* W1    = (const float*)d_in[2];
    const float* a1s   = (const float*)d_in[3];
    const float* a1d   = (const float*)d_in[4];
    const float* b1    = (const float*)d_in[5];
    const float* W2    = (const float*)d_in[6];
    const float* a2s   = (const float*)d_in[7];
    const float* a2d   = (const float*)d_in[8];
    const float* b2    = (const float*)d_in[9];
    const float* fc1_w = (const float*)d_in[10];
    const float* fc1_b = (const float*)d_in[11];
    const float* g1    = (const float*)d_in[12];
    const float* be1   = (const float*)d_in[13];
    const float* fc2_w = (const float*)d_in[14];
    const float* fc2_b = (const float*)d_in[15];
    const float* g2    = (const float*)d_in[16];
    const float* be2   = (const float*)d_in[17];
    const float* lin_w = (const float*)d_in[18];
    const float* lin_b = (const float*)d_in[19];
    float* out = (float*)d_out;

    // workspace carve-up (256B aligned)
    char* ws = (char*)d_ws;
    auto alloc = [&](size_t bytes) {
        void* p = (void*)ws;
        ws += (bytes + 255) & ~size_t(255);
        return p;
    };
    unsigned short* h_bf    = (unsigned short*)alloc((size_t)NN * DD * 2); // ping
    unsigned short* act_bf  = (unsigned short*)alloc((size_t)NN * DD * 2); // pong
    unsigned short* W1t     = (unsigned short*)alloc((size_t)DD * FIN * 2);
    unsigned short* fc1t    = (unsigned short*)alloc((size_t)DD * DD * 2);
    unsigned short* W2t     = (unsigned short*)alloc((size_t)DD * DD * 2);
    unsigned short* fc2t    = (unsigned short*)alloc((size_t)DD * DD * 2);
    float*          al_s    = (float*)alloc((size_t)NN * 8 * 4);           // layer-1 logits (H=8)
    float*          al_d    = (float*)alloc((size_t)NN * 8 * 4);
    float*          al_s2   = (float*)alloc((size_t)NN * 4);               // layer-2 logits (H=1, zeroed in prep)
    float*          al_d2   = (float*)alloc((size_t)NN * 4);
    int*            row_ptr = (int*)alloc((size_t)(NN + 1) * 4);
    int*            deg     = (int*)alloc((size_t)NN * 4);
    int*            cnt2    = (int*)alloc((size_t)NN * NCH * 4);           // per-(dst,chunk) counts
    int*            base2   = (int*)alloc((size_t)NN * NCH * 4);           // per-(dst,chunk) bases
    int*            cur2    = (int*)alloc((size_t)NN * NCH * 4);           // per-(dst,chunk) cursors
    int*            csr_src = (int*)alloc((size_t)ET * 4);
    int*            flag    = (int*)alloc(256);
    float*          bnstatA = (float*)alloc(1024 * 4);                     // fc1 stats (zeroed in prep)
    float*          bnstatB = (float*)alloc(1024 * 4);                     // fc2 stats (zeroed in prep)
    float*          bias2f  = (float*)alloc(512 * 4);                      // BN1-fold bias for W2 GEMM

    // --- edge index canonicalization + src-chunk-sorted CSR build ---
    init_k<<<(NN + 255) / 256, 256, 0, stream>>>(deg, cnt2, cur2, (const unsigned*)ei, flag);
    count_deg<<<(EE + 255) / 256, 256, 0, stream>>>(ei, flag, deg, cnt2);
    scan_k<<<1, 1024, 0, stream>>>(deg, row_ptr);
    base_k<<<(NN + 255) / 256, 256, 0, stream>>>(row_ptr, cnt2, base2);
    fill_csr<<<(ET + 255) / 256, 256, 0, stream>>>(ei, flag, base2, cur2, csr_src);

    // --- merged: weight transpose (LDS-tiled) + x conversion + zero-init aux ---
    unsigned short* x_bf = act_bf; // consumed by GEMM1 before gat_gather_k overwrites
    const int prep_blocks = TBLK + (SZ_X + SZ_Z + 255) / 256;
    prep_all_k<<<prep_blocks, 256, 0, stream>>>(x, W1, fc1_w, W2, fc2_w,
                                                x_bf, W1t, fc1t, W2t, fc2t,
                                                bnstatA, bnstatB, al_s2, al_d2);

    const int GB = 640; // 160 padded m-tiles x 4 n-tiles, XCD-swizzled in-kernel

    // ---------------- Layer 1: GATConv(128 -> 8 x 64) ----------------
    // h1 = x @ W1 (bf16 out) + fused logits
    gemm_bf16<0, 0, 0, 1, 8><<<GB, 256, 0, stream>>>(
        x_bf, W1t, nullptr, h_bf, nullptr, a1s, a1d, al_s, al_d, NN, DD, FIN);
    gat_gather_k<8><<<NN / 4, 256, 0, stream>>>(h_bf, al_s, al_d, row_ptr, csr_src, b1, act_bf);
    // r1 = relu(agg1 @ fc1 + b) (bf16 out) + fused BN stats
    gemm_bf16<1, 1, 1, 0, 8><<<GB, 256, 0, stream>>>(
        act_bf, fc1t, fc1_b, h_bf, bnstatA, nullptr, nullptr, nullptr, nullptr, NN, DD, DD);
    // fold BN1 into W2 weights + bias
    fold1_k<<<128, 256, 0, stream>>>(bnstatA, g1, be1, W2t, bias2f);

    // ---------------- Layer 2: GATConv(512 -> 1 x 512) ----------------
    // h2 = r1 @ (sc*W2) + (sh@W2) (bf16 out) + fused logits (H=1: atomic into zeroed bufs)
    gemm_bf16<0, 1, 0, 1, 1><<<GB, 256, 0, stream>>>(
        h_bf, W2t, bias2f, act_bf, nullptr, a2s, a2d, al_s2, al_d2, NN, DD, DD);
    gat_gather_k<1><<<NN / 4, 256, 0, stream>>>(act_bf, al_s2, al_d2, row_ptr, csr_src, b2, h_bf);
    // r2 = relu(agg2 @ fc2 + b) (bf16 out) + fused BN stats
    gemm_bf16<1, 1, 1, 0, 8><<<GB, 256, 0, stream>>>(
        h_bf, fc2t, fc2_b, act_bf, bnstatB, nullptr, nullptr, nullptr, nullptr, NN, DD, DD);

    // ---------------- head: BN2 computed inline in final_linear ----------------
    final_linear<<<(NN + 3) / 4, 256, 0, stream>>>(act_bf, bnstatB, g2, be2, lin_w, lin_b, out);
}

// Round 14
// 366.713 us; speedup vs baseline: 1.0282x; 1.0282x over previous
//
#include <hip/hip_runtime.h>
#include <hip/hip_bf16.h>

// Problem constants (fixed by reference)
static constexpr int NN = 20000;   // nodes
static constexpr int EE = 320000;  // edges (without self loops)
static constexpr int ET = EE + NN; // edges incl self loops = 340000
static constexpr int DD = 512;     // hidden dim
static constexpr int FIN = 128;    // input features

typedef __attribute__((ext_vector_type(8))) short short8; // 8 bf16 (4 VGPRs)
typedef __attribute__((ext_vector_type(4))) float f32x4;  // MFMA C/D frag

// float -> bf16 (round to nearest even), raw ushort bits
__device__ __forceinline__ unsigned short f2bf(float f) {
    unsigned u = __float_as_uint(f);
    u += 0x7fffu + ((u >> 16) & 1u);
    return (unsigned short)(u >> 16);
}
__device__ __forceinline__ float bf2f(unsigned short b) {
    return __uint_as_float(((unsigned)b) << 16);
}

// async global->LDS DMA, 16 B per lane. LDS dest = wave-uniform base + lane*16.
__device__ __forceinline__ void async_copy16(short* lds, const unsigned short* g) {
    __builtin_amdgcn_global_load_lds(
        (const __attribute__((address_space(1))) unsigned int*)g,
        (__attribute__((address_space(3))) unsigned int*)lds,
        16, 0, 0);
}

// ---------- init: deg/cursor + edge-index dtype detection ----------
__global__ void init_k(int* __restrict__ deg, int* __restrict__ cursor,
                       const unsigned* __restrict__ ei, int* __restrict__ flag) {
    int i = blockIdx.x * blockDim.x + threadIdx.x;
    if (i < NN) { deg[i] = 1; cursor[i] = 0; } // self-loop pre-counted
    if (i == 0) {
        int is64 = 1;
        for (int j = 0; j < 64; ++j)
            if (ei[2 * j + 1] != 0u) { is64 = 0; break; }
        *flag = is64;
    }
}

// count in-degree of real edges, decoding edge_index directly (no int32 copy)
__global__ void count_deg(const void* __restrict__ ei, const int* __restrict__ flag,
                          int* __restrict__ deg) {
    int i = blockIdx.x * blockDim.x + threadIdx.x;
    if (i >= EE) return;
    int d = (*flag) ? (int)((const long long*)ei)[EE + i] : ((const int*)ei)[EE + i];
    atomicAdd(&deg[d], 1);
}

__global__ void scan_k(const int* __restrict__ deg, int* __restrict__ row_ptr) {
    __shared__ int part[1024];
    int t = threadIdx.x;
    const int CH = (NN + 1023) / 1024; // 20
    int start = t * CH;
    int end = min(start + CH, NN);
    int s = 0;
    for (int i = start; i < end; ++i) s += deg[i];
    part[t] = s;
    __syncthreads();
    for (int off = 1; off < 1024; off <<= 1) {
        int v = 0;
        if (t >= off) v = part[t - off];
        __syncthreads();
        part[t] += v;
        __syncthreads();
    }
    int base = (t == 0) ? 0 : part[t - 1];
    for (int i = start; i < end; ++i) { row_ptr[i] = base; base += deg[i]; }
    if (t == 1023) row_ptr[NN] = part[1023];
}

// store the SRC node id directly in CSR order, decoding edge_index directly
__global__ void fill_csr(const void* __restrict__ ei, const int* __restrict__ flag,
                         const int* __restrict__ row_ptr, int* __restrict__ cursor,
                         int* __restrict__ csr_src) {
    int e = blockIdx.x * blockDim.x + threadIdx.x;
    if (e >= ET) return;
    int s, d;
    if (e < EE) {
        if (*flag) {
            const long long* p = (const long long*)ei;
            s = (int)p[e]; d = (int)p[EE + e];
        } else {
            const int* p = (const int*)ei;
            s = p[e]; d = p[EE + e];
        }
    } else {
        s = d = e - EE;
    }
    int pos = atomicAdd(&cursor[d], 1);
    csr_src[row_ptr[d] + pos] = s;
}

// ---------- merged prep: LDS-tiled weight transpose (blocks 0..207) + x->bf16 + zero-init ----------
static constexpr int TBLK = 208;                // transpose tile blocks (16 + 3*64)
static constexpr int SZ_X = NN * FIN;           // 2,560,000
static constexpr int SZ_Z = 2 * 1024 + 2 * NN;  // bnstatA/B + al_s2 + al_d2
__global__ __launch_bounds__(256) void prep_all_k(
    const float* __restrict__ x, const float* __restrict__ W1,
    const float* __restrict__ fc1, const float* __restrict__ W2,
    const float* __restrict__ fc2,
    unsigned short* __restrict__ xb, unsigned short* __restrict__ W1t,
    unsigned short* __restrict__ fc1t, unsigned short* __restrict__ W2t,
    unsigned short* __restrict__ fc2t,
    float* __restrict__ bnstatA, float* __restrict__ bnstatB,
    float* __restrict__ al_s2, float* __restrict__ al_d2) {
    int b = blockIdx.x;
    if (b < TBLK) { // 64x64 transpose tiles, coalesced reads AND writes
        __shared__ unsigned short tile[64][65];
        const float* src; unsigned short* dst; int rows, cols;
        if (b < 16)       { src = W1;  dst = W1t;  rows = FIN; cols = DD; }
        else if (b < 80)  { b -= 16;  src = fc1; dst = fc1t; rows = DD; cols = DD; }
        else if (b < 144) { b -= 80;  src = W2;  dst = W2t;  rows = DD; cols = DD; }
        else              { b -= 144; src = fc2; dst = fc2t; rows = DD; cols = DD; }
        int tc = cols / 64;
        int r0 = (b / tc) * 64, c0 = (b % tc) * 64;
        int t = threadIdx.x, lr = t >> 6, lc = t & 63;
#pragma unroll
        for (int p = 0; p < 16; ++p) {
            int r = lr + p * 4;
            tile[r][lc] = f2bf(src[(size_t)(r0 + r) * cols + c0 + lc]);
        }
        __syncthreads();
#pragma unroll
        for (int p = 0; p < 16; ++p) {
            int r = lr + p * 4; // output row = source col
            dst[(size_t)(c0 + r) * rows + r0 + lc] = tile[lc][r];
        }
        return;
    }
    int i = (b - TBLK) * 256 + threadIdx.x;
    if (i < SZ_X) { xb[i] = f2bf(x[i]); return; }
    i -= SZ_X;
    if (i < 1024) { bnstatA[i] = 0.f; return; }
    i -= 1024;
    if (i < 1024) { bnstatB[i] = 0.f; return; }
    i -= 1024;
    if (i < NN) { al_s2[i] = 0.f; return; }
    i -= NN;
    if (i < NN) { al_d2[i] = 0.f; return; }
}

// ---------- bf16 MFMA GEMM: Cb[M,Nc] = bf16( A[M,K] @ Bt[Nc,K]^T (+bias)(+relu) ) ----------
// 128x128 tile, BK=64 (two 32-elem half-tiles), 256 threads = 4 waves (2x2),
// each wave 4x4 tiles of 16x16x32. Staging via async global_load_lds (16 B/lane).
// XCD-aware swizzle: 640 blocks (160 padded m-tiles x 4 n-tiles);
// bm = 8*(id/32) + id%8, bn = (id/8)&3.
// STATS: fused per-column BN sum/sumsq of post-relu fp32 C into bnstat.
// ALS: fused attention logits al_s/al_d = C . avs/avd (per row, per head).
template <int RELU, int HASBIAS, int STATS, int ALS, int H>
__global__ __launch_bounds__(256) void gemm_bf16(const unsigned short* __restrict__ A,
                                                 const unsigned short* __restrict__ Bt,
                                                 const float* __restrict__ bias,
                                                 unsigned short* __restrict__ Cb,
                                                 float* __restrict__ bnstat,
                                                 const float* __restrict__ avs,
                                                 const float* __restrict__ avd,
                                                 float* __restrict__ al_s,
                                                 float* __restrict__ al_d,
                                                 int M, int Nc, int K) {
    int id = blockIdx.x;
    int bm = ((id >> 5) << 3) + (id & 7); // 0..159
    int bn = (id >> 3) & 3;               // 0..3
    int m0 = bm * 128, n0 = bn * 128;
    if (m0 >= M) return; // padded m-tiles: whole block exits (no barrier executed)

    __shared__ short As0[128 * 32], As1[128 * 32]; // k-halves, 8 KB each
    __shared__ short Bs0[128 * 32], Bs1[128 * 32];
    int t = threadIdx.x;
    int lane = t & 63, w = t >> 6;
    int wm = w & 1, wn = w >> 1;           // wave quadrant (2x2 of 64x64)
    int quad = lane >> 4, mr = lane & 15;  // MFMA fragment indices
    int lrow = lane >> 2;                  // staging: row within 16-row group
    int lcol = (lane & 3) * 8;             // staging: elem offset within 32-elem half-row

    const unsigned short* Ag0 = A + (size_t)(m0 + w * 32 + lrow) * K + lcol;
    const unsigned short* Ag1 = A + (size_t)(m0 + w * 32 + 16 + lrow) * K + lcol;
    const unsigned short* Bg0 = Bt + (size_t)(n0 + w * 32 + lrow) * K + lcol;
    const unsigned short* Bg1 = Bt + (size_t)(n0 + w * 32 + 16 + lrow) * K + lcol;
    short* Al[2][2] = {{&As0[(w * 32) * 32], &As0[(w * 32 + 16) * 32]},
                       {&As1[(w * 32) * 32], &As1[(w * 32 + 16) * 32]}};
    short* Bl[2][2] = {{&Bs0[(w * 32) * 32], &Bs0[(w * 32 + 16) * 32]},
                       {&Bs1[(w * 32) * 32], &Bs1[(w * 32 + 16) * 32]}};

    f32x4 zero = {0.f, 0.f, 0.f, 0.f};
    f32x4 acc[4][4];
#pragma unroll
    for (int i = 0; i < 4; ++i)
#pragma unroll
        for (int j = 0; j < 4; ++j) acc[i][j] = zero;

    for (int k0 = 0; k0 < K; k0 += 64) {
        async_copy16(Al[0][0], Ag0 + k0);
        async_copy16(Al[1][0], Ag0 + k0 + 32);
        async_copy16(Al[0][1], Ag1 + k0);
        async_copy16(Al[1][1], Ag1 + k0 + 32);
        async_copy16(Bl[0][0], Bg0 + k0);
        async_copy16(Bl[1][0], Bg0 + k0 + 32);
        async_copy16(Bl[0][1], Bg1 + k0);
        async_copy16(Bl[1][1], Bg1 + k0 + 32);
        __syncthreads(); // drains vmcnt(0): DMA data landed in LDS
#pragma unroll
        for (int kp = 0; kp < 2; ++kp) {
            const short* Sa = kp ? As1 : As0;
            const short* Sb = kp ? Bs1 : Bs0;
            short8 af[4], bfr[4];
#pragma unroll
            for (int i = 0; i < 4; ++i) {
                af[i]  = *(const short8*)(&Sa[(wm * 64 + i * 16 + mr) * 32 + quad * 8]);
                bfr[i] = *(const short8*)(&Sb[(wn * 64 + i * 16 + mr) * 32 + quad * 8]);
            }
#pragma unroll
            for (int i = 0; i < 4; ++i)
#pragma unroll
                for (int j = 0; j < 4; ++j)
                    acc[i][j] = __builtin_amdgcn_mfma_f32_16x16x32_bf16(af[i], bfr[j], acc[i][j], 0, 0, 0);
        }
        __syncthreads(); // all waves done reading before next DMA overwrites
    }

    // epilogue: C/D layout col = lane&15, row = (lane>>4)*4 + reg  [m89/m91]
    float as_j[4], ad_j[4];
    if (ALS) {
#pragma unroll
        for (int j = 0; j < 4; ++j) {
            int n = n0 + wn * 64 + j * 16 + mr;
            as_j[j] = avs[n]; // a[H][C] flat == global col index for both H=8 and H=1
            ad_j[j] = avd[n];
        }
    }
    const int head = (H == 8) ? ((n0 + wn * 64) >> 6) : 0;
    float sj[4] = {0.f, 0.f, 0.f, 0.f}, qj[4] = {0.f, 0.f, 0.f, 0.f};
#pragma unroll
    for (int i = 0; i < 4; ++i) {
        int mb = m0 + wm * 64 + i * 16 + quad * 4;
#pragma unroll
        for (int r = 0; r < 4; ++r) {
            int m = mb + r;               // uniform across the 16 mr-lanes
            bool valid = (m < M);
            float ps = 0.f, pd = 0.f;
#pragma unroll
            for (int j = 0; j < 4; ++j) {
                int n = n0 + wn * 64 + j * 16 + mr;
                float v = acc[i][j][r];
                if (HASBIAS) v += bias[n];
                if (RELU) v = fmaxf(v, 0.f);
                unsigned short hb = f2bf(v);
                if (valid) Cb[(size_t)m * Nc + n] = hb;
                if (ALS) {
                    float vv = bf2f(hb); // match downstream bf16 read
                    ps += as_j[j] * vv;
                    pd += ad_j[j] * vv;
                }
                if (STATS && valid) { sj[j] += v; qj[j] += v * v; }
            }
            if (ALS) {
                ps += __shfl_xor(ps, 1); pd += __shfl_xor(pd, 1);
                ps += __shfl_xor(ps, 2); pd += __shfl_xor(pd, 2);
                ps += __shfl_xor(ps, 4); pd += __shfl_xor(pd, 4);
                ps += __shfl_xor(ps, 8); pd += __shfl_xor(pd, 8);
                if (mr == 0 && valid) {
                    if (H == 8) { al_s[m * 8 + head] = ps; al_d[m * 8 + head] = pd; }
                    else        { atomicAdd(&al_s[m], ps); atomicAdd(&al_d[m], pd); }
                }
            }
        }
    }
    if (STATS) {
#pragma unroll
        for (int j = 0; j < 4; ++j) {
            float s = sj[j], q = qj[j];
            s += __shfl_xor(s, 16); q += __shfl_xor(q, 16);
            s += __shfl_xor(s, 32); q += __shfl_xor(q, 32);
            if (lane < 16) { // quad==0 holds the 4-row-group total for this column
                int n = n0 + wn * 64 + j * 16 + mr;
                atomicAdd(&bnstat[n], s);
                atomicAdd(&bnstat[512 + n], q);
            }
        }
    }
}

// ---------- fused softmax + gather-aggregate: one WAVE per node ----------
template <int H>
__global__ __launch_bounds__(256) void gat_gather_k(const unsigned short* __restrict__ hb,
                                                    const float* __restrict__ al_s,
                                                    const float* __restrict__ al_d,
                                                    const int* __restrict__ row_ptr,
                                                    const int* __restrict__ csr_src,
                                                    const float* __restrict__ bias,
                                                    unsigned short* __restrict__ outb) {
    int t = threadIdx.x;
    int w = t >> 6, lane = t & 63;
    int n = blockIdx.x * 4 + w; // NN % 4 == 0
    int beg = row_ptr[n], end = row_ptr[n + 1];
    const int hh = (H == 8) ? (lane >> 3) : 0;
    float ald = al_d[n * H + hh];
    float psum = 0.f;
    float acc[8] = {0.f, 0.f, 0.f, 0.f, 0.f, 0.f, 0.f, 0.f};

    for (int p0 = beg; p0 < end; p0 += 64) {
        int cnt = min(64, end - p0);
        int sv = (p0 + lane < end) ? csr_src[p0 + lane] : 0;
        int p = 0;
        for (; p + 8 <= cnt; p += 8) {
            int sn[8];
#pragma unroll
            for (int u = 0; u < 8; ++u) sn[u] = __shfl(sv, p + u);
            float l[8];
#pragma unroll
            for (int u = 0; u < 8; ++u) l[u] = al_s[sn[u] * H + hh] + ald;
            short8 hv[8];
#pragma unroll
            for (int u = 0; u < 8; ++u)
                hv[u] = *(const short8*)(hb + (size_t)sn[u] * DD + lane * 8);
            float a[8];
#pragma unroll
            for (int u = 0; u < 8; ++u) {
                float xx = l[u];
                a[u] = __expf((xx > 0.f) ? xx : 0.2f * xx);
                psum += a[u];
            }
#pragma unroll
            for (int u = 0; u < 8; ++u)
#pragma unroll
                for (int j = 0; j < 8; ++j) acc[j] += a[u] * bf2f((unsigned short)hv[u][j]);
        }
        for (; p < cnt; ++p) {
            int sn0 = __shfl(sv, p);
            float l0 = al_s[sn0 * H + hh] + ald;
            short8 h0 = *(const short8*)(hb + (size_t)sn0 * DD + lane * 8);
            float a0 = __expf((l0 > 0.f) ? l0 : 0.2f * l0);
            psum += a0;
#pragma unroll
            for (int j = 0; j < 8; ++j) acc[j] += a0 * bf2f((unsigned short)h0[j]);
        }
    }
    float inv = 1.0f / psum;
    unsigned short ov[8];
#pragma unroll
    for (int j = 0; j < 8; ++j) ov[j] = f2bf(acc[j] * inv + bias[lane * 8 + j]);
    *(int4*)(outb + (size_t)n * DD + lane * 8) = *(const int4*)ov;
}

// ---------- fold BN1 into W2: W2t[n][k] *= sc[k] (in place); bias2[n] = sum_k sh[k]*W2t[n][k] ----------
__global__ __launch_bounds__(256) void fold1_k(const float* __restrict__ stat,
                                               const float* __restrict__ g,
                                               const float* __restrict__ be,
                                               unsigned short* __restrict__ W2t,
                                               float* __restrict__ bias2) {
    int t = threadIdx.x;
    int n = blockIdx.x * 4 + (t >> 6); // 128 blocks -> n in [0,512)
    int lane = t & 63;
    float pb = 0.f;
#pragma unroll
    for (int j = 0; j < 8; ++j) {
        int k = lane * 8 + j;
        float mean = stat[k] * (1.0f / NN);
        float var = stat[512 + k] * (1.0f / NN) - mean * mean;
        float sc = g[k] * rsqrtf(var + 1e-5f);
        float sh = be[k] - mean * sc;
        float wv = bf2f(W2t[n * DD + k]);
        W2t[n * DD + k] = f2bf(sc * wv);
        pb += sh * wv;
    }
    for (int off = 32; off; off >>= 1) pb += __shfl_down(pb, off);
    if (lane == 0) bias2[n] = pb;
}

// ---------- final linear [D,2] + relu (wave per node), BN2 computed inline per lane ----------
__global__ void final_linear(const unsigned short* __restrict__ xb,
                             const float* __restrict__ stat, const float* __restrict__ g,
                             const float* __restrict__ be, const float* __restrict__ w,
                             const float* __restrict__ b, float* __restrict__ out) {
    int wave = (blockIdx.x * blockDim.x + threadIdx.x) >> 6;
    int lane = threadIdx.x & 63;
    if (wave >= NN) return;
    short8 hv = *(const short8*)(xb + (size_t)wave * DD + lane * 8);
    float p0 = 0.f, p1 = 0.f;
#pragma unroll
    for (int j = 0; j < 8; ++j) {
        int c = lane * 8 + j;
        float mean = stat[c] * (1.0f / NN);
        float var = stat[512 + c] * (1.0f / NN) - mean * mean;
        float sc = g[c] * rsqrtf(var + 1e-5f);
        float vn = (bf2f((unsigned short)hv[j]) - mean) * sc + be[c];
        p0 += vn * w[2 * c];
        p1 += vn * w[2 * c + 1];
    }
    for (int off = 32; off; off >>= 1) {
        p0 += __shfl_down(p0, off);
        p1 += __shfl_down(p1, off);
    }
    if (lane == 0) {
        out[wave * 2 + 0] = fmaxf(p0 + b[0], 0.f);
        out[wave * 2 + 1] = fmaxf(p1 + b[1], 0.f);
    }
}

extern "C" void kernel_launch(void* const* d_in, const int* in_sizes, int n_in,
                              void* d_out, int out_size, void* d_ws, size_t ws_size,
                              hipStream_t stream) {
    const float* x     = (const float*)d_in[0];
    const void*  ei    = d_in[1];
    const float* W1    = (const float*)d_in[2];
    const float* a1s   = (const float*)d_in[3];
    const float* a1d   = (const float*)d_in[4];
    const float* b1    = (const float*)d_in[5];
    const float* W2    = (const float*)d_in[6];
    const float* a2s   = (const float*)d_in[7];
    const float* a2d   = (const float*)d_in[8];
    const float* b2    = (const float*)d_in[9];
    const float* fc1_w = (const float*)d_in[10];
    const float* fc1_b = (const float*)d_in[11];
    const float* g1    = (const float*)d_in[12];
    const float* be1   = (const float*)d_in[13];
    const float* fc2_w = (const float*)d_in[14];
    const float* fc2_b = (const float*)d_in[15];
    const float* g2    = (const float*)d_in[16];
    const float* be2   = (const float*)d_in[17];
    const float* lin_w = (const float*)d_in[18];
    const float* lin_b = (const float*)d_in[19];
    float* out = (float*)d_out;

    // workspace carve-up (256B aligned)
    char* ws = (char*)d_ws;
    auto alloc = [&](size_t bytes) {
        void* p = (void*)ws;
        ws += (bytes + 255) & ~size_t(255);
        return p;
    };
    unsigned short* h_bf    = (unsigned short*)alloc((size_t)NN * DD * 2); // ping
    unsigned short* act_bf  = (unsigned short*)alloc((size_t)NN * DD * 2); // pong
    unsigned short* W1t     = (unsigned short*)alloc((size_t)DD * FIN * 2);
    unsigned short* fc1t    = (unsigned short*)alloc((size_t)DD * DD * 2);
    unsigned short* W2t     = (unsigned short*)alloc((size_t)DD * DD * 2);
    unsigned short* fc2t    = (unsigned short*)alloc((size_t)DD * DD * 2);
    float*          al_s    = (float*)alloc((size_t)NN * 8 * 4);           // layer-1 logits (H=8)
    float*          al_d    = (float*)alloc((size_t)NN * 8 * 4);
    float*          al_s2   = (float*)alloc((size_t)NN * 4);               // layer-2 logits (H=1, zeroed in prep)
    float*          al_d2   = (float*)alloc((size_t)NN * 4);
    int*            row_ptr = (int*)alloc((size_t)(NN + 1) * 4);
    int*            deg     = (int*)alloc((size_t)NN * 4);
    int*            cursor  = (int*)alloc((size_t)NN * 4);
    int*            csr_src = (int*)alloc((size_t)ET * 4);
    int*            flag    = (int*)alloc(256);
    float*          bnstatA = (float*)alloc(1024 * 4);                     // fc1 stats (zeroed in prep)
    float*          bnstatB = (float*)alloc(1024 * 4);                     // fc2 stats (zeroed in prep)
    float*          bias2f  = (float*)alloc(512 * 4);                      // BN1-fold bias for W2 GEMM

    // --- edge index canonicalization + CSR build (decode ei directly; graph shared) ---
    init_k<<<(NN + 255) / 256, 256, 0, stream>>>(deg, cursor, (const unsigned*)ei, flag);
    count_deg<<<(EE + 255) / 256, 256, 0, stream>>>(ei, flag, deg);
    scan_k<<<1, 1024, 0, stream>>>(deg, row_ptr);
    fill_csr<<<(ET + 255) / 256, 256, 0, stream>>>(ei, flag, row_ptr, cursor, csr_src);

    // --- merged: weight transpose (LDS-tiled) + x conversion + zero-init aux ---
    unsigned short* x_bf = act_bf; // consumed by GEMM1 before gat_gather_k overwrites
    const int prep_blocks = TBLK + (SZ_X + SZ_Z + 255) / 256;
    prep_all_k<<<prep_blocks, 256, 0, stream>>>(x, W1, fc1_w, W2, fc2_w,
                                                x_bf, W1t, fc1t, W2t, fc2t,
                                                bnstatA, bnstatB, al_s2, al_d2);

    const int GB = 640; // 160 padded m-tiles x 4 n-tiles, XCD-swizzled in-kernel

    // ---------------- Layer 1: GATConv(128 -> 8 x 64) ----------------
    // h1 = x @ W1 (bf16 out) + fused logits
    gemm_bf16<0, 0, 0, 1, 8><<<GB, 256, 0, stream>>>(
        x_bf, W1t, nullptr, h_bf, nullptr, a1s, a1d, al_s, al_d, NN, DD, FIN);
    gat_gather_k<8><<<NN / 4, 256, 0, stream>>>(h_bf, al_s, al_d, row_ptr, csr_src, b1, act_bf);
    // r1 = relu(agg1 @ fc1 + b) (bf16 out) + fused BN stats
    gemm_bf16<1, 1, 1, 0, 8><<<GB, 256, 0, stream>>>(
        act_bf, fc1t, fc1_b, h_bf, bnstatA, nullptr, nullptr, nullptr, nullptr, NN, DD, DD);
    // fold BN1 into W2 weights + bias
    fold1_k<<<128, 256, 0, stream>>>(bnstatA, g1, be1, W2t, bias2f);

    // ---------------- Layer 2: GATConv(512 -> 1 x 512) ----------------
    // h2 = r1 @ (sc*W2) + (sh@W2) (bf16 out) + fused logits (H=1: atomic into zeroed bufs)
    gemm_bf16<0, 1, 0, 1, 1><<<GB, 256, 0, stream>>>(
        h_bf, W2t, bias2f, act_bf, nullptr, a2s, a2d, al_s2, al_d2, NN, DD, DD);
    gat_gather_k<1><<<NN / 4, 256, 0, stream>>>(act_bf, al_s2, al_d2, row_ptr, csr_src, b2, h_bf);
    // r2 = relu(agg2 @ fc2 + b) (bf16 out) + fused BN stats
    gemm_bf16<1, 1, 1, 0, 8><<<GB, 256, 0, stream>>>(
        h_bf, fc2t, fc2_b, act_bf, bnstatB, nullptr, nullptr, nullptr, nullptr, NN, DD, DD);

    // ---------------- head: BN2 computed inline in final_linear ----------------
    final_linear<<<(NN + 3) / 4, 256, 0, stream>>>(act_bf, bnstatB, g2, be2, lin_w, lin_b, out);
}